// Round 4
// baseline (452.998 us; speedup 1.0000x reference)
//
#include <hip/hip_runtime.h>
#include <hip/hip_bf16.h>

typedef short short8 __attribute__((ext_vector_type(8)));
typedef float f32x4 __attribute__((ext_vector_type(4)));

constexpr int BDIM = 32, RDIM = 64, CDIM = 96;
constexpr int LTOK = RDIM * RDIM;      // 4096
constexpr int GG = 64;
constexpr int NWIN = 2048;
constexpr float SCALE = 0.17677669529663687f;
constexpr long OUT1OFF = (long)BDIM * LTOK * CDIM;   // 12582912

// ws layout (bf16 element offsets): transposed weights [n][k], k-contiguous
constexpr int O_WQKVT = 0;        // [288][96]
constexpr int O_WPROJT = 27648;   // [96][96]
constexpr int O_WFC1T = 36864;    // [384][96]
constexpr int O_WFC2T = 73728;    // [96][384]
constexpr int W_TOT = 110592;

__device__ __forceinline__ unsigned short f2b(float f) {
  return __builtin_bit_cast(unsigned short, __float2bfloat16(f));
}
__device__ __forceinline__ float b2f(unsigned short u) {
  return __bfloat162float(__builtin_bit_cast(__hip_bfloat16, u));
}

// ---------------- weight transpose+cvt prep (proven round 3) ----------------
__global__ void prep_weights(const float* __restrict__ wqkv,
                             const float* __restrict__ wproj,
                             const float* __restrict__ wfc1,
                             const float* __restrict__ wfc2,
                             unsigned short* __restrict__ ws) {
  int i = blockIdx.x * 256 + threadIdx.x;
  if (i >= W_TOT) return;
  float v;
  if (i < O_WPROJT) {
    int n = i / 96, k = i - n * 96;
    v = wqkv[k * 288 + n];
  } else if (i < O_WFC1T) {
    int j = i - O_WPROJT, n = j / 96, k = j - n * 96;
    v = wproj[k * 96 + n];
  } else if (i < O_WFC2T) {
    int j = i - O_WFC1T, n = j / 96, k = j - n * 96;
    v = wfc1[k * 384 + n];
  } else {
    int j = i - O_WFC2T, n = j / 384, k = j - n * 384;
    v = wfc2[k * 96 + n];
  }
  ws[i] = f2b(v);
}

// =====================================================================
// Fused kernel: one 8x8 window per block, 4 waves.
// LN1 -> per-head {qkv, S, softmax(+out1), PV+LePE, proj-accum} -> x1
// -> LN2 -> hidden-streamed fc1+GELU+fc2 -> out0 = x1 + mlp.
// LDS 39.5 KB -> 4 blocks/CU; __launch_bounds__(256,4) caps VGPR<=128.
// Wave-private row ownership: MLP phase needs zero barriers.
// =====================================================================
__global__ __launch_bounds__(256, 4)
void fused_block(const float* __restrict__ x, const float* __restrict__ bqkv,
                 const float* __restrict__ wlepe, const float* __restrict__ blepe,
                 const float* __restrict__ bproj, const float* __restrict__ g1,
                 const float* __restrict__ bt1, const float* __restrict__ g2v,
                 const float* __restrict__ bt2, const float* __restrict__ bfc1,
                 const float* __restrict__ bfc2,
                 const unsigned short* __restrict__ ws, float* __restrict__ out) {
  constexpr int SA = 104;  // hA stride: 208 B rows, 16B-aligned
  constexpr int SQ = 72;   // qkS/Htile stride: 144 B rows, 16B-aligned
  constexpr int SV = 72;   // vS stride
  constexpr int SP = 72;   // pS stride
  constexpr int SO = 32;   // oS stride (64 B rows)
  __shared__ __attribute__((aligned(16))) unsigned short hA[64 * SA];  // h -> h2
  __shared__ __attribute__((aligned(16))) unsigned short qkS[64 * SQ]; // q|k -> Htile
  __shared__ __attribute__((aligned(16))) unsigned short vS[32 * SV];
  __shared__ __attribute__((aligned(16))) unsigned short pS[64 * SP];  // P; red overlay
  __shared__ __attribute__((aligned(16))) unsigned short oS[64 * SO];
  float* red = (float*)pS;

  const int tid = threadIdx.x, lane = tid & 63;
  const int wv = __builtin_amdgcn_readfirstlane(tid >> 6);
  const int w = blockIdx.x, b = w >> 6, wi = w & 63, wr = wi >> 3, wc = wi & 7;
  const long xbase = (long)b * (LTOK * CDIM);
  const int l15 = lane & 15, quad = lane >> 4, lk = quad * 8, lr = quad * 4;

  // ---- load + LN1: thread owns (token=lane, channel-quarter=wv) ----
  {
    const int tok = lane;
    const long rowbase =
        xbase + (long)((wr * 8 + (tok >> 3)) * RDIM + wc * 8 + (tok & 7)) * CDIM;
    float xv[24], s1 = 0.f, s2 = 0.f;
#pragma unroll
    for (int i = 0; i < 24; ++i) {
      float v = x[rowbase + wv * 24 + i];
      xv[i] = v; s1 += v; s2 += v * v;
    }
    red[wv * 64 + tok] = s1;
    red[256 + wv * 64 + tok] = s2;
    __syncthreads();
    float m = 0.f, vv = 0.f;
#pragma unroll
    for (int q = 0; q < 4; ++q) { m += red[q * 64 + tok]; vv += red[256 + q * 64 + tok]; }
    m *= (1.f / 96.f);
    vv = vv * (1.f / 96.f) - m * m;
    float rs = rsqrtf(vv + 1e-5f);
#pragma unroll
    for (int j = 0; j < 3; ++j) {   // packed 16B LDS writes
      short8 hp;
#pragma unroll
      for (int e = 0; e < 8; ++e) {
        int c = wv * 24 + j * 8 + e;
        ((unsigned short*)&hp)[e] = f2b((xv[j * 8 + e] - m) * rs * g1[c] + bt1[c]);
      }
      *(short8*)&hA[lane * SA + wv * 24 + j * 8] = hp;
    }
  }
  __syncthreads();

  // ---- hoist A-fragments of h (wave-own rows; hA LDS dead afterwards) ----
  short8 Afrag[3];
#pragma unroll
  for (int kk = 0; kk < 3; ++kk)
    Afrag[kk] = *(const short8*)&hA[(wv * 16 + l15) * SA + kk * 32 + lk];

  f32x4 accP[6];
#pragma unroll
  for (int t = 0; t < 6; ++t) accP[t] = (f32x4){0.f, 0.f, 0.f, 0.f};

  // ---- per-head attention ----
#pragma unroll 1
  for (int h = 0; h < 3; ++h) {
    // qkv for this head: 6 n-tiles (q0,q1,k0,k1,v0,v1) x 3 k-steps
    f32x4 acc[6];
#pragma unroll
    for (int t = 0; t < 6; ++t) acc[t] = (f32x4){0.f, 0.f, 0.f, 0.f};
#pragma unroll
    for (int kk = 0; kk < 3; ++kk) {
#pragma unroll
      for (int t = 0; t < 6; ++t) {
        int n = (t < 2 ? h * 32 + t * 16
                       : t < 4 ? 96 + h * 32 + (t - 2) * 16
                               : 192 + h * 32 + (t - 4) * 16) + l15;
        short8 bw = *(const short8*)&ws[O_WQKVT + n * 96 + kk * 32 + lk];
        acc[t] = __builtin_amdgcn_mfma_f32_16x16x32_bf16(Afrag[kk], bw, acc[t], 0, 0, 0);
      }
    }
    // stage q (scaled) | k into qkS, v into vS (transposed)
#pragma unroll
    for (int t = 0; t < 6; ++t) {
      int n = (t < 2 ? h * 32 + t * 16
                     : t < 4 ? 96 + h * 32 + (t - 2) * 16
                             : 192 + h * 32 + (t - 4) * 16) + l15;
      float bias = bqkv[n];
#pragma unroll
      for (int r = 0; r < 4; ++r) {
        int row = wv * 16 + lr + r;
        float v = acc[t][r] + bias;
        if (t < 2) qkS[row * SQ + t * 16 + l15] = f2b(v * SCALE);
        else if (t < 4) qkS[row * SQ + 32 + (t - 2) * 16 + l15] = f2b(v);
        else vS[((t - 4) * 16 + l15) * SV + row] = f2b(v);
      }
    }
    __syncthreads();

    // S = q k^T (wave's 16 rows x 64 cols)
    short8 aq = *(const short8*)&qkS[(wv * 16 + l15) * SQ + lk];
    f32x4 sacc[4];
#pragma unroll
    for (int t = 0; t < 4; ++t) sacc[t] = (f32x4){0.f, 0.f, 0.f, 0.f};
#pragma unroll
    for (int nt = 0; nt < 4; ++nt) {
      short8 bk = *(const short8*)&qkS[(nt * 16 + l15) * SQ + 32 + lk];
      sacc[nt] = __builtin_amdgcn_mfma_f32_16x16x32_bf16(aq, bk, sacc[nt], 0, 0, 0);
    }
    // softmax across nt-tiles + 16-lane groups
    float p[4][4];
#pragma unroll
    for (int r = 0; r < 4; ++r) {
      float mx = -1e30f;
#pragma unroll
      for (int nt = 0; nt < 4; ++nt) mx = fmaxf(mx, sacc[nt][r]);
#pragma unroll
      for (int s = 1; s < 16; s <<= 1) mx = fmaxf(mx, __shfl_xor(mx, s, 64));
      float sum = 0.f;
#pragma unroll
      for (int nt = 0; nt < 4; ++nt) {
        float e = __expf(sacc[nt][r] - mx);
        p[nt][r] = e; sum += e;
      }
#pragma unroll
      for (int s = 1; s < 16; s <<= 1) sum += __shfl_xor(sum, s, 64);
      float inv = 1.f / sum;
#pragma unroll
      for (int nt = 0; nt < 4; ++nt) p[nt][r] *= inv;
    }
    // write attn probs (fp32 out1) + stage P (wave-own rows)
    const long o1base = OUT1OFF + ((long)(w * 3 + h) * GG) * GG;
#pragma unroll
    for (int nt = 0; nt < 4; ++nt) {
      int col = nt * 16 + l15;
#pragma unroll
      for (int r = 0; r < 4; ++r) {
        int row = wv * 16 + lr + r;
        out[o1base + (long)row * GG + col] = p[nt][r];
        pS[row * SP + col] = f2b(p[nt][r]);
      }
    }
    // PV (pS wave-own; vS covered by stage barrier)
    f32x4 oa[2];
    oa[0] = (f32x4){0.f, 0.f, 0.f, 0.f};
    oa[1] = (f32x4){0.f, 0.f, 0.f, 0.f};
#pragma unroll
    for (int kk = 0; kk < 2; ++kk) {
      short8 ap = *(const short8*)&pS[(wv * 16 + l15) * SP + kk * 32 + lk];
#pragma unroll
      for (int nt = 0; nt < 2; ++nt) {
        short8 bv = *(const short8*)&vS[(nt * 16 + l15) * SV + kk * 32 + lk];
        oa[nt] = __builtin_amdgcn_mfma_f32_16x16x32_bf16(ap, bv, oa[nt], 0, 0, 0);
      }
    }
    // LePE + stage O rows (wave-own)
#pragma unroll
    for (int nt = 0; nt < 2; ++nt) {
      int dl = nt * 16 + l15, c = h * 32 + dl;
      float lw[9];
#pragma unroll
      for (int q = 0; q < 9; ++q) lw[q] = wlepe[c * 9 + q];
      float lb = blepe[c];
#pragma unroll
      for (int r = 0; r < 4; ++r) {
        int row = wv * 16 + lr + r;
        int tr_ = row >> 3, tc_ = row & 7;
        float a = lb;
#pragma unroll
        for (int kh = 0; kh < 3; ++kh)
#pragma unroll
          for (int kw = 0; kw < 3; ++kw) {
            int rr = tr_ + kh - 1, cc = tc_ + kw - 1;
            if (rr >= 0 && rr < 8 && cc >= 0 && cc < 8)
              a += lw[kh * 3 + kw] * b2f(vS[dl * SV + rr * 8 + cc]);
          }
        oS[row * SO + dl] = f2b(oa[nt][r] + a);
      }
    }
    // proj partial for this head (oS wave-own rows, same wave wrote them)
    {
      short8 ao = *(const short8*)&oS[(wv * 16 + l15) * SO + lk];
#pragma unroll
      for (int nt = 0; nt < 6; ++nt) {
        short8 bw = *(const short8*)&ws[O_WPROJT + (nt * 16 + l15) * 96 + h * 32 + lk];
        accP[nt] = __builtin_amdgcn_mfma_f32_16x16x32_bf16(ao, bw, accP[nt], 0, 0, 0);
      }
    }
    __syncthreads();  // protect qkS/vS before next head's staging
  }

  // ---- x1 = x + proj + bias (regs) ----
  float x1v[6][4];
#pragma unroll
  for (int nt = 0; nt < 6; ++nt) {
    int ch = nt * 16 + l15;
    float bias = bproj[ch];
#pragma unroll
    for (int r = 0; r < 4; ++r) {
      int row = wv * 16 + lr + r;
      long g = xbase + (long)((wr * 8 + (row >> 3)) * RDIM + wc * 8 + (row & 7)) * CDIM + ch;
      x1v[nt][r] = x[g] + accP[nt][r] + bias;
    }
  }

  // ---- LN2 (in-register, 16-lane shuffle reductions per row) ----
  float mr[4], rsr[4];
#pragma unroll
  for (int r = 0; r < 4; ++r) {
    float s = 0.f, q = 0.f;
#pragma unroll
    for (int nt = 0; nt < 6; ++nt) { float v = x1v[nt][r]; s += v; q += v * v; }
#pragma unroll
    for (int sh = 1; sh < 16; sh <<= 1) {
      s += __shfl_xor(s, sh, 64);
      q += __shfl_xor(q, sh, 64);
    }
    float m = s * (1.f / 96.f);
    float var = q * (1.f / 96.f) - m * m;
    mr[r] = m; rsr[r] = rsqrtf(var + 1e-5f);
  }
  // h2 -> hA (wave-own rows; hA dead since A-frag hoist)
#pragma unroll
  for (int nt = 0; nt < 6; ++nt) {
    int ch = nt * 16 + l15;
    float gg = g2v[ch], bb = bt2[ch];
#pragma unroll
    for (int r = 0; r < 4; ++r) {
      int row = wv * 16 + lr + r;
      hA[row * SA + ch] = f2b((x1v[nt][r] - mr[r]) * rsr[r] * gg + bb);
    }
  }
  short8 A2[3];
#pragma unroll
  for (int kk = 0; kk < 3; ++kk)
    A2[kk] = *(const short8*)&hA[(wv * 16 + l15) * SA + kk * 32 + lk];

  // ---- MLP: stream hidden dim in 64-col tiles through Htile (= qkS) ----
  unsigned short* Ht = qkS;
  f32x4 accF[6];
#pragma unroll
  for (int t = 0; t < 6; ++t) accF[t] = (f32x4){0.f, 0.f, 0.f, 0.f};
#pragma unroll 1
  for (int ht = 0; ht < 6; ++ht) {
    f32x4 a1[4];
#pragma unroll
    for (int t = 0; t < 4; ++t) a1[t] = (f32x4){0.f, 0.f, 0.f, 0.f};
#pragma unroll
    for (int kk = 0; kk < 3; ++kk) {
#pragma unroll
      for (int nt = 0; nt < 4; ++nt) {
        int n = ht * 64 + nt * 16 + l15;
        short8 bw = *(const short8*)&ws[O_WFC1T + n * 96 + kk * 32 + lk];
        a1[nt] = __builtin_amdgcn_mfma_f32_16x16x32_bf16(A2[kk], bw, a1[nt], 0, 0, 0);
      }
    }
#pragma unroll
    for (int nt = 0; nt < 4; ++nt) {
      int n = ht * 64 + nt * 16 + l15;
      float bias = bfc1[n];
#pragma unroll
      for (int r = 0; r < 4; ++r) {
        float v = a1[nt][r] + bias;
        float gl = 0.5f * v * (1.f + erff(v * 0.70710678118654752f));
        Ht[(wv * 16 + lr + r) * SQ + nt * 16 + l15] = f2b(gl);
      }
    }
    // fc2 partial (Htile rows wave-own; no barrier needed)
#pragma unroll
    for (int kk = 0; kk < 2; ++kk) {
      short8 ah = *(const short8*)&Ht[(wv * 16 + l15) * SQ + kk * 32 + lk];
#pragma unroll
      for (int nt = 0; nt < 6; ++nt) {
        short8 bw = *(const short8*)&ws[O_WFC2T + (nt * 16 + l15) * 384 + ht * 64 + kk * 32 + lk];
        accF[nt] = __builtin_amdgcn_mfma_f32_16x16x32_bf16(ah, bw, accF[nt], 0, 0, 0);
      }
    }
  }

  // ---- epilogue: out0 = x1 + mlp + bias ----
#pragma unroll
  for (int nt = 0; nt < 6; ++nt) {
    int ch = nt * 16 + l15;
    float bias = bfc2[ch];
#pragma unroll
    for (int r = 0; r < 4; ++r) {
      int row = wv * 16 + lr + r;
      long g = xbase + (long)((wr * 8 + (row >> 3)) * RDIM + wc * 8 + (row & 7)) * CDIM + ch;
      out[g] = x1v[nt][r] + accF[nt][r] + bias;
    }
  }
}

extern "C" void kernel_launch(void* const* d_in, const int* in_sizes, int n_in,
                              void* d_out, int out_size, void* d_ws, size_t ws_size,
                              hipStream_t stream) {
  const float* x = (const float*)d_in[0];
  const float* w_qkv = (const float*)d_in[1];
  const float* b_qkv = (const float*)d_in[2];
  const float* w_lepe = (const float*)d_in[3];
  const float* b_lepe = (const float*)d_in[4];
  const float* w_proj = (const float*)d_in[5];
  const float* b_proj = (const float*)d_in[6];
  const float* g1 = (const float*)d_in[7];
  const float* bt1 = (const float*)d_in[8];
  const float* g2 = (const float*)d_in[9];
  const float* bt2 = (const float*)d_in[10];
  const float* w_fc1 = (const float*)d_in[11];
  const float* b_fc1 = (const float*)d_in[12];
  const float* w_fc2 = (const float*)d_in[13];
  const float* b_fc2 = (const float*)d_in[14];
  float* out = (float*)d_out;
  unsigned short* ws = (unsigned short*)d_ws;

  prep_weights<<<(W_TOT + 255) / 256, 256, 0, stream>>>(w_qkv, w_proj, w_fc1, w_fc2, ws);
  fused_block<<<NWIN, 256, 0, stream>>>(x, b_qkv, w_lepe, b_lepe, b_proj, g1, bt1,
                                        g2, bt2, b_fc1, b_fc2, ws, out);
}

// Round 5
// 431.032 us; speedup vs baseline: 1.0510x; 1.0510x over previous
//
#include <hip/hip_runtime.h>
#include <hip/hip_bf16.h>

typedef short short8 __attribute__((ext_vector_type(8)));
typedef float f32x4 __attribute__((ext_vector_type(4)));
typedef unsigned short ushort4v __attribute__((ext_vector_type(4)));

constexpr int BDIM = 32, RDIM = 64, CDIM = 96;
constexpr int LTOK = RDIM * RDIM;      // 4096
constexpr int GG = 64;
constexpr int NWIN = 2048;
constexpr float SCALE = 0.17677669529663687f;
constexpr long OUT1OFF = (long)BDIM * LTOK * CDIM;   // 12582912

// ws layout (bf16 element offsets): transposed weights [n][k], k-contiguous
constexpr int O_WQKVT = 0;        // [288][96]
constexpr int O_WPROJT = 27648;   // [96][96]
constexpr int O_WFC1T = 36864;    // [384][96]
constexpr int O_WFC2T = 73728;    // [96][384]
constexpr int W_TOT = 110592;

__device__ __forceinline__ unsigned short f2b(float f) {
  return __builtin_bit_cast(unsigned short, __float2bfloat16(f));
}
__device__ __forceinline__ float b2f(unsigned short u) {
  return __bfloat162float(__builtin_bit_cast(__hip_bfloat16, u));
}

// ---------------- weight transpose+cvt prep (proven round 3) ----------------
__global__ void prep_weights(const float* __restrict__ wqkv,
                             const float* __restrict__ wproj,
                             const float* __restrict__ wfc1,
                             const float* __restrict__ wfc2,
                             unsigned short* __restrict__ ws) {
  int i = blockIdx.x * 256 + threadIdx.x;
  if (i >= W_TOT) return;
  float v;
  if (i < O_WPROJT) {
    int n = i / 96, k = i - n * 96;
    v = wqkv[k * 288 + n];
  } else if (i < O_WFC1T) {
    int j = i - O_WPROJT, n = j / 96, k = j - n * 96;
    v = wproj[k * 96 + n];
  } else if (i < O_WFC2T) {
    int j = i - O_WFC1T, n = j / 96, k = j - n * 96;
    v = wfc1[k * 384 + n];
  } else {
    int j = i - O_WFC2T, n = j / 384, k = j - n * 384;
    v = wfc2[k * 96 + n];
  }
  ws[i] = f2b(v);
}

// =====================================================================
// Fused kernel: one 8x8 window per block, 4 waves.
// LN1 -> per-head {qkv, S, softmax, PV+LePE, proj-accum, coalesced out1}
// -> x1 -> LN2 -> hidden-streamed fc1+GELU+fc2 -> coalesced out0.
// LDS 39.5 KB -> 4 blocks/CU. All global stores are full-line float4.
// =====================================================================
__global__ __launch_bounds__(256, 4)
void fused_block(const float* __restrict__ x, const float* __restrict__ bqkv,
                 const float* __restrict__ wlepe, const float* __restrict__ blepe,
                 const float* __restrict__ bproj, const float* __restrict__ g1,
                 const float* __restrict__ bt1, const float* __restrict__ g2v,
                 const float* __restrict__ bt2, const float* __restrict__ bfc1,
                 const float* __restrict__ bfc2,
                 const unsigned short* __restrict__ ws, float* __restrict__ out) {
  constexpr int SA = 104;  // hA stride: 208 B rows, 16B-aligned
  constexpr int SQ = 72;   // qkS/Htile stride
  constexpr int SV = 72;   // vS stride
  constexpr int SP = 72;   // pS stride
  constexpr int SO = 32;   // oS stride
  __shared__ __attribute__((aligned(16))) unsigned short hA[64 * SA];  // h -> h2 -> out0
  __shared__ __attribute__((aligned(16))) unsigned short qkS[64 * SQ]; // q|k -> Htile
  __shared__ __attribute__((aligned(16))) unsigned short vS[32 * SV];
  __shared__ __attribute__((aligned(16))) unsigned short pS[64 * SP];  // P; red overlay
  __shared__ __attribute__((aligned(16))) unsigned short oS[64 * SO];
  float* red = (float*)pS;

  const int tid = threadIdx.x, lane = tid & 63;
  const int wv = __builtin_amdgcn_readfirstlane(tid >> 6);
  const int w = blockIdx.x, b = w >> 6, wi = w & 63, wr = wi >> 3, wc = wi & 7;
  const long xbase = (long)b * (LTOK * CDIM);
  const int l15 = lane & 15, quad = lane >> 4, lk = quad * 8, lr = quad * 4;

  // ---- load + LN1: thread owns (token=lane, channel-quarter=wv) ----
  {
    const int tok = lane;
    const long rowbase =
        xbase + (long)((wr * 8 + (tok >> 3)) * RDIM + wc * 8 + (tok & 7)) * CDIM;
    f32x4 xq[6];
#pragma unroll
    for (int j = 0; j < 6; ++j) xq[j] = *(const f32x4*)&x[rowbase + wv * 24 + j * 4];
    float s1 = 0.f, s2 = 0.f;
#pragma unroll
    for (int j = 0; j < 6; ++j)
#pragma unroll
      for (int e = 0; e < 4; ++e) { float v = xq[j][e]; s1 += v; s2 += v * v; }
    red[wv * 64 + tok] = s1;
    red[256 + wv * 64 + tok] = s2;
    __syncthreads();
    float m = 0.f, vv = 0.f;
#pragma unroll
    for (int q = 0; q < 4; ++q) { m += red[q * 64 + tok]; vv += red[256 + q * 64 + tok]; }
    m *= (1.f / 96.f);
    vv = vv * (1.f / 96.f) - m * m;
    float rs = rsqrtf(vv + 1e-5f);
#pragma unroll
    for (int j = 0; j < 3; ++j) {   // packed 16B LDS writes
      short8 hp;
#pragma unroll
      for (int e = 0; e < 8; ++e) {
        int c = wv * 24 + j * 8 + e;
        float xv = xq[(j * 8 + e) >> 2][(j * 8 + e) & 3];
        ((unsigned short*)&hp)[e] = f2b((xv - m) * rs * g1[c] + bt1[c]);
      }
      *(short8*)&hA[lane * SA + wv * 24 + j * 8] = hp;
    }
  }
  __syncthreads();

  // ---- hoist A-fragments of h (wave-own rows; hA LDS dead afterwards) ----
  short8 Afrag[3];
#pragma unroll
  for (int kk = 0; kk < 3; ++kk)
    Afrag[kk] = *(const short8*)&hA[(wv * 16 + l15) * SA + kk * 32 + lk];

  f32x4 accP[6];
#pragma unroll
  for (int t = 0; t < 6; ++t) accP[t] = (f32x4){0.f, 0.f, 0.f, 0.f};

  // ---- per-head attention ----
#pragma unroll 1
  for (int h = 0; h < 3; ++h) {
    // qkv for this head: 6 n-tiles (q0,q1,k0,k1,v0,v1) x 3 k-steps
    f32x4 acc[6];
#pragma unroll
    for (int t = 0; t < 6; ++t) acc[t] = (f32x4){0.f, 0.f, 0.f, 0.f};
#pragma unroll
    for (int kk = 0; kk < 3; ++kk) {
#pragma unroll
      for (int t = 0; t < 6; ++t) {
        int n = (t < 2 ? h * 32 + t * 16
                       : t < 4 ? 96 + h * 32 + (t - 2) * 16
                               : 192 + h * 32 + (t - 4) * 16) + l15;
        short8 bw = *(const short8*)&ws[O_WQKVT + n * 96 + kk * 32 + lk];
        acc[t] = __builtin_amdgcn_mfma_f32_16x16x32_bf16(Afrag[kk], bw, acc[t], 0, 0, 0);
      }
    }
    // stage q (scaled) | k into qkS, v into vS (transposed)
#pragma unroll
    for (int t = 0; t < 6; ++t) {
      int n = (t < 2 ? h * 32 + t * 16
                     : t < 4 ? 96 + h * 32 + (t - 2) * 16
                             : 192 + h * 32 + (t - 4) * 16) + l15;
      float bias = bqkv[n];
#pragma unroll
      for (int r = 0; r < 4; ++r) {
        int row = wv * 16 + lr + r;
        float v = acc[t][r] + bias;
        if (t < 2) qkS[row * SQ + t * 16 + l15] = f2b(v * SCALE);
        else if (t < 4) qkS[row * SQ + 32 + (t - 2) * 16 + l15] = f2b(v);
        else vS[((t - 4) * 16 + l15) * SV + row] = f2b(v);
      }
    }
    __syncthreads();   // qkS/vS complete

    // S = q k^T (wave's 16 rows x 64 cols)
    short8 aq = *(const short8*)&qkS[(wv * 16 + l15) * SQ + lk];
    f32x4 sacc[4];
#pragma unroll
    for (int t = 0; t < 4; ++t) sacc[t] = (f32x4){0.f, 0.f, 0.f, 0.f};
#pragma unroll
    for (int nt = 0; nt < 4; ++nt) {
      short8 bk = *(const short8*)&qkS[(nt * 16 + l15) * SQ + 32 + lk];
      sacc[nt] = __builtin_amdgcn_mfma_f32_16x16x32_bf16(aq, bk, sacc[nt], 0, 0, 0);
    }
    // softmax across nt-tiles + 16-lane groups
    float p[4][4];
#pragma unroll
    for (int r = 0; r < 4; ++r) {
      float mx = -1e30f;
#pragma unroll
      for (int nt = 0; nt < 4; ++nt) mx = fmaxf(mx, sacc[nt][r]);
#pragma unroll
      for (int s = 1; s < 16; s <<= 1) mx = fmaxf(mx, __shfl_xor(mx, s, 64));
      float sum = 0.f;
#pragma unroll
      for (int nt = 0; nt < 4; ++nt) {
        float e = __expf(sacc[nt][r] - mx);
        p[nt][r] = e; sum += e;
      }
#pragma unroll
      for (int s = 1; s < 16; s <<= 1) sum += __shfl_xor(sum, s, 64);
      float inv = 1.f / sum;
#pragma unroll
      for (int nt = 0; nt < 4; ++nt) p[nt][r] *= inv;
    }
    // stage P (wave-own rows) — out1 written coalesced after barrier
#pragma unroll
    for (int nt = 0; nt < 4; ++nt) {
      int col = nt * 16 + l15;
#pragma unroll
      for (int r = 0; r < 4; ++r) pS[(wv * 16 + lr + r) * SP + col] = f2b(p[nt][r]);
    }
    // PV (pS wave-own rows; vS covered by stage barrier)
    f32x4 oa[2];
    oa[0] = (f32x4){0.f, 0.f, 0.f, 0.f};
    oa[1] = (f32x4){0.f, 0.f, 0.f, 0.f};
#pragma unroll
    for (int kk = 0; kk < 2; ++kk) {
      short8 ap = *(const short8*)&pS[(wv * 16 + l15) * SP + kk * 32 + lk];
#pragma unroll
      for (int nt = 0; nt < 2; ++nt) {
        short8 bv = *(const short8*)&vS[(nt * 16 + l15) * SV + kk * 32 + lk];
        oa[nt] = __builtin_amdgcn_mfma_f32_16x16x32_bf16(ap, bv, oa[nt], 0, 0, 0);
      }
    }
    // LePE + stage O rows (wave-own)
#pragma unroll
    for (int nt = 0; nt < 2; ++nt) {
      int dl = nt * 16 + l15, c = h * 32 + dl;
      float lw[9];
#pragma unroll
      for (int q = 0; q < 9; ++q) lw[q] = wlepe[c * 9 + q];
      float lb = blepe[c];
#pragma unroll
      for (int r = 0; r < 4; ++r) {
        int row = wv * 16 + lr + r;
        int tr_ = row >> 3, tc_ = row & 7;
        float a = lb;
#pragma unroll
        for (int kh = 0; kh < 3; ++kh)
#pragma unroll
          for (int kw = 0; kw < 3; ++kw) {
            int rr = tr_ + kh - 1, cc = tc_ + kw - 1;
            if (rr >= 0 && rr < 8 && cc >= 0 && cc < 8)
              a += lw[kh * 3 + kw] * b2f(vS[dl * SV + rr * 8 + cc]);
          }
        oS[row * SO + dl] = f2b(oa[nt][r] + a);
      }
    }
    // proj partial for this head (oS wave-own rows, same wave wrote them)
    {
      short8 ao = *(const short8*)&oS[(wv * 16 + l15) * SO + lk];
#pragma unroll
      for (int nt = 0; nt < 6; ++nt) {
        short8 bw = *(const short8*)&ws[O_WPROJT + (nt * 16 + l15) * 96 + h * 32 + lk];
        accP[nt] = __builtin_amdgcn_mfma_f32_16x16x32_bf16(ao, bw, accP[nt], 0, 0, 0);
      }
    }
    __syncthreads();   // pS complete; qkS/vS reads done before next head

    // ---- coalesced out1 write: 16 KB flat, 1 KB/instr full lines ----
    {
      const long o1 = OUT1OFF + (long)(w * 3 + h) * 4096;
#pragma unroll
      for (int k2 = 0; k2 < 4; ++k2) {
        int f = k2 * 1024 + tid * 4;          // flat float idx in [0,4096)
        int row = f >> 6, col = f & 63;
        ushort4v us = *(const ushort4v*)&pS[row * SP + col];
        f32x4 o4;
        o4[0] = b2f(us[0]); o4[1] = b2f(us[1]);
        o4[2] = b2f(us[2]); o4[3] = b2f(us[3]);
        *(f32x4*)&out[o1 + f] = o4;
      }
    }
  }

  // ---- x1 = x + proj + bias (regs; x re-read is block-L2-resident) ----
  float x1v[6][4];
#pragma unroll
  for (int nt = 0; nt < 6; ++nt) {
    int ch = nt * 16 + l15;
    float bias = bproj[ch];
#pragma unroll
    for (int r = 0; r < 4; ++r) {
      int row = wv * 16 + lr + r;
      long g = xbase + (long)((wr * 8 + (row >> 3)) * RDIM + wc * 8 + (row & 7)) * CDIM + ch;
      x1v[nt][r] = x[g] + accP[nt][r] + bias;
    }
  }

  // ---- LN2 (in-register, 16-lane shuffle reductions per row) ----
  float mr[4], rsr[4];
#pragma unroll
  for (int r = 0; r < 4; ++r) {
    float s = 0.f, q = 0.f;
#pragma unroll
    for (int nt = 0; nt < 6; ++nt) { float v = x1v[nt][r]; s += v; q += v * v; }
#pragma unroll
    for (int sh = 1; sh < 16; sh <<= 1) {
      s += __shfl_xor(s, sh, 64);
      q += __shfl_xor(q, sh, 64);
    }
    float m = s * (1.f / 96.f);
    float var = q * (1.f / 96.f) - m * m;
    mr[r] = m; rsr[r] = rsqrtf(var + 1e-5f);
  }
  // h2 -> hA (wave-own rows; hA dead since A-frag hoist)
#pragma unroll
  for (int nt = 0; nt < 6; ++nt) {
    int ch = nt * 16 + l15;
    float gg = g2v[ch], bb = bt2[ch];
#pragma unroll
    for (int r = 0; r < 4; ++r) {
      int row = wv * 16 + lr + r;
      hA[row * SA + ch] = f2b((x1v[nt][r] - mr[r]) * rsr[r] * gg + bb);
    }
  }
  short8 A2[3];
#pragma unroll
  for (int kk = 0; kk < 3; ++kk)
    A2[kk] = *(const short8*)&hA[(wv * 16 + l15) * SA + kk * 32 + lk];

  // ---- MLP: stream hidden dim in 64-col tiles through Htile (= qkS) ----
  unsigned short* Ht = qkS;
  f32x4 accF[6];
#pragma unroll
  for (int t = 0; t < 6; ++t) accF[t] = (f32x4){0.f, 0.f, 0.f, 0.f};
#pragma unroll 1
  for (int ht = 0; ht < 6; ++ht) {
    f32x4 a1[4];
#pragma unroll
    for (int t = 0; t < 4; ++t) a1[t] = (f32x4){0.f, 0.f, 0.f, 0.f};
#pragma unroll
    for (int kk = 0; kk < 3; ++kk) {
#pragma unroll
      for (int nt = 0; nt < 4; ++nt) {
        int n = ht * 64 + nt * 16 + l15;
        short8 bw = *(const short8*)&ws[O_WFC1T + n * 96 + kk * 32 + lk];
        a1[nt] = __builtin_amdgcn_mfma_f32_16x16x32_bf16(A2[kk], bw, a1[nt], 0, 0, 0);
      }
    }
#pragma unroll
    for (int nt = 0; nt < 4; ++nt) {
      int n = ht * 64 + nt * 16 + l15;
      float bias = bfc1[n];
#pragma unroll
      for (int r = 0; r < 4; ++r) {
        float v = a1[nt][r] + bias;
        float gl = 0.5f * v * (1.f + erff(v * 0.70710678118654752f));
        Ht[(wv * 16 + lr + r) * SQ + nt * 16 + l15] = f2b(gl);
      }
    }
    // fc2 partial (Htile rows wave-own; no barrier needed)
#pragma unroll
    for (int kk = 0; kk < 2; ++kk) {
      short8 ah = *(const short8*)&Ht[(wv * 16 + l15) * SQ + kk * 32 + lk];
#pragma unroll
      for (int nt = 0; nt < 6; ++nt) {
        short8 bw = *(const short8*)&ws[O_WFC2T + (nt * 16 + l15) * 384 + ht * 64 + kk * 32 + lk];
        accF[nt] = __builtin_amdgcn_mfma_f32_16x16x32_bf16(ah, bw, accF[nt], 0, 0, 0);
      }
    }
  }

  // ---- epilogue: stage out0 bf16 (wave-own rows), then coalesced write ----
#pragma unroll
  for (int nt = 0; nt < 6; ++nt) {
    int ch = nt * 16 + l15;
    float bias = bfc2[ch];
#pragma unroll
    for (int r = 0; r < 4; ++r) {
      int row = wv * 16 + lr + r;
      hA[row * SA + ch] = f2b(x1v[nt][r] + accF[nt][r] + bias);
    }
  }
  __syncthreads();
  {
    const long obase = xbase + (long)((wr * 8) * RDIM + wc * 8) * CDIM;
#pragma unroll
    for (int k2 = 0; k2 < 6; ++k2) {
      int f = k2 * 1024 + tid * 4;            // flat float idx in [0,6144)
      int wrow = f / 768, off = f - wrow * 768;
      int tir = off / 96, ch = off - tir * 96;
      ushort4v us = *(const ushort4v*)&hA[(wrow * 8 + tir) * SA + ch];
      f32x4 o4;
      o4[0] = b2f(us[0]); o4[1] = b2f(us[1]);
      o4[2] = b2f(us[2]); o4[3] = b2f(us[3]);
      *(f32x4*)&out[obase + (long)wrow * (RDIM * CDIM) + tir * 96 + ch] = o4;
    }
  }
}

extern "C" void kernel_launch(void* const* d_in, const int* in_sizes, int n_in,
                              void* d_out, int out_size, void* d_ws, size_t ws_size,
                              hipStream_t stream) {
  const float* x = (const float*)d_in[0];
  const float* w_qkv = (const float*)d_in[1];
  const float* b_qkv = (const float*)d_in[2];
  const float* w_lepe = (const float*)d_in[3];
  const float* b_lepe = (const float*)d_in[4];
  const float* w_proj = (const float*)d_in[5];
  const float* b_proj = (const float*)d_in[6];
  const float* g1 = (const float*)d_in[7];
  const float* bt1 = (const float*)d_in[8];
  const float* g2 = (const float*)d_in[9];
  const float* bt2 = (const float*)d_in[10];
  const float* w_fc1 = (const float*)d_in[11];
  const float* b_fc1 = (const float*)d_in[12];
  const float* w_fc2 = (const float*)d_in[13];
  const float* b_fc2 = (const float*)d_in[14];
  float* out = (float*)d_out;
  unsigned short* ws = (unsigned short*)d_ws;

  prep_weights<<<(W_TOT + 255) / 256, 256, 0, stream>>>(w_qkv, w_proj, w_fc1, w_fc2, ws);
  fused_block<<<NWIN, 256, 0, stream>>>(x, b_qkv, w_lepe, b_lepe, b_proj, g1, bt1,
                                        g2, bt2, b_fc1, b_fc2, ws, out);
}